// Round 1
// baseline (707.541 us; speedup 1.0000x reference)
//
#include <hip/hip_runtime.h>

// Problem constants (from reference): B=16, C=128, H=256, W=256, K=2, S=2
// Output: (16, 128, 128, 128) fp32
#define CC 128
#define HH 256
#define WW 256
#define OH 128
#define OW 128

__global__ __launch_bounds__(256) void mixgb_kernel(
    const float* __restrict__ x,
    const float* __restrict__ maxgate,   // (C,1,2,2) flat: c*4 + ky*2 + kx
    const float* __restrict__ avggate,
    const float* __restrict__ mb,        // (C,)
    const float* __restrict__ ab,        // (C,)
    float* __restrict__ out)
{
    // 64 threads per output row (each thread -> 2 output pixels).
    int tid = blockIdx.x * 256 + threadIdx.x;
    int t   = tid & 63;          // position within output row
    int row = tid >> 6;          // flat (b*C + c, oh)
    int oh  = row & (OH - 1);
    int bc  = row >> 7;          // b*C + c
    int c   = bc & (CC - 1);

    const float* xin = x + (size_t)bc * (HH * WW) + (size_t)(2 * oh) * WW + 4 * t;
    float4 r0 = *reinterpret_cast<const float4*>(xin);        // input row 2*oh
    float4 r1 = *reinterpret_cast<const float4*>(xin + WW);   // input row 2*oh+1

    float4 mg = *reinterpret_cast<const float4*>(maxgate + 4 * c);
    float4 ag = *reinterpret_cast<const float4*>(avggate + 4 * c);
    float mbv = mb[c];
    float abv = ab[c];

    // Output pixel 0: 2x2 block {r0.x, r0.y; r1.x, r1.y}
    float mx0 = fmaxf(fmaxf(r0.x, r0.y), fmaxf(r1.x, r1.y));
    float av0 = (r0.x + r0.y + r1.x + r1.y) * 0.25f;
    float mw0 = fmaf(r0.x, mg.x, fmaf(r0.y, mg.y, fmaf(r1.x, mg.z, fmaf(r1.y, mg.w, mbv))));
    float aw0 = fmaf(r0.x, ag.x, fmaf(r0.y, ag.y, fmaf(r1.x, ag.z, fmaf(r1.y, ag.w, abv))));
    float o0  = mx0 * mw0 + av0 * aw0;

    // Output pixel 1: 2x2 block {r0.z, r0.w; r1.z, r1.w}
    float mx1 = fmaxf(fmaxf(r0.z, r0.w), fmaxf(r1.z, r1.w));
    float av1 = (r0.z + r0.w + r1.z + r1.w) * 0.25f;
    float mw1 = fmaf(r0.z, mg.x, fmaf(r0.w, mg.y, fmaf(r1.z, mg.z, fmaf(r1.w, mg.w, mbv))));
    float aw1 = fmaf(r0.z, ag.x, fmaf(r0.w, ag.y, fmaf(r1.z, ag.z, fmaf(r1.w, ag.w, abv))));
    float o1  = mx1 * mw1 + av1 * aw1;

    *reinterpret_cast<float2*>(out + (size_t)row * OW + 2 * t) = make_float2(o0, o1);
}

extern "C" void kernel_launch(void* const* d_in, const int* in_sizes, int n_in,
                              void* d_out, int out_size, void* d_ws, size_t ws_size,
                              hipStream_t stream) {
    const float* x  = (const float*)d_in[0];
    const float* mg = (const float*)d_in[1];
    const float* ag = (const float*)d_in[2];
    const float* mb = (const float*)d_in[3];
    const float* ab = (const float*)d_in[4];
    float* out = (float*)d_out;

    // total threads = B*C*OH * 64 = 16*128*128*64 = 16,777,216 -> 65536 blocks of 256
    const int total_threads = 16 * CC * OH * 64;
    dim3 grid(total_threads / 256);
    mixgb_kernel<<<grid, 256, 0, stream>>>(x, mg, ag, mb, ab, out);
}

// Round 6
// 689.153 us; speedup vs baseline: 1.0267x; 1.0267x over previous
//
#include <hip/hip_runtime.h>

// Problem: B=16, C=128, H=256, W=256, K=2, S=2 -> out (16,128,128,128) fp32
#define CC 128
#define HH 256
#define WW 256
#define OH 128
#define OW 128

typedef float floatx4 __attribute__((ext_vector_type(4)));

__global__ __launch_bounds__(256) void mixgb_kernel(
    const float* __restrict__ x,
    const float* __restrict__ maxgate,   // (C,1,2,2) flat: c*4 + ky*2 + kx
    const float* __restrict__ avggate,
    const float* __restrict__ mb,        // (C,)
    const float* __restrict__ ab,        // (C,)
    float* __restrict__ out)
{
    // 32 threads per output row; each thread -> 4 output pixels (one 16B store).
    int tid = blockIdx.x * 256 + threadIdx.x;
    int t   = tid & 31;          // position within output row (4-pixel chunks)
    int row = tid >> 5;          // flat (b*C + c, oh)
    int oh  = row & (OH - 1);
    int bc  = row >> 7;          // b*C + c
    int c   = bc & (CC - 1);

    const float* xin = x + (size_t)bc * (HH * WW) + (size_t)(2 * oh) * WW + 8 * t;
    // input row 2*oh: 8 floats; row 2*oh+1: 8 floats (nontemporal: read-once stream)
    floatx4 a0 = __builtin_nontemporal_load(reinterpret_cast<const floatx4*>(xin));
    floatx4 a1 = __builtin_nontemporal_load(reinterpret_cast<const floatx4*>(xin + 4));
    floatx4 b0 = __builtin_nontemporal_load(reinterpret_cast<const floatx4*>(xin + WW));
    floatx4 b1 = __builtin_nontemporal_load(reinterpret_cast<const floatx4*>(xin + WW + 4));

    floatx4 mg = *reinterpret_cast<const floatx4*>(maxgate + 4 * c);
    floatx4 ag = *reinterpret_cast<const floatx4*>(avggate + 4 * c);
    float mbv = mb[c];
    float abv = ab[c];

    floatx4 o;
    {   // pixel 0: {a0[0],a0[1]; b0[0],b0[1]}
        float mx = fmaxf(fmaxf(a0[0], a0[1]), fmaxf(b0[0], b0[1]));
        float av = (a0[0] + a0[1] + b0[0] + b0[1]) * 0.25f;
        float mw = fmaf(a0[0], mg[0], fmaf(a0[1], mg[1], fmaf(b0[0], mg[2], fmaf(b0[1], mg[3], mbv))));
        float aw = fmaf(a0[0], ag[0], fmaf(a0[1], ag[1], fmaf(b0[0], ag[2], fmaf(b0[1], ag[3], abv))));
        o[0] = mx * mw + av * aw;
    }
    {   // pixel 1: {a0[2],a0[3]; b0[2],b0[3]}
        float mx = fmaxf(fmaxf(a0[2], a0[3]), fmaxf(b0[2], b0[3]));
        float av = (a0[2] + a0[3] + b0[2] + b0[3]) * 0.25f;
        float mw = fmaf(a0[2], mg[0], fmaf(a0[3], mg[1], fmaf(b0[2], mg[2], fmaf(b0[3], mg[3], mbv))));
        float aw = fmaf(a0[2], ag[0], fmaf(a0[3], ag[1], fmaf(b0[2], ag[2], fmaf(b0[3], ag[3], abv))));
        o[1] = mx * mw + av * aw;
    }
    {   // pixel 2: {a1[0],a1[1]; b1[0],b1[1]}
        float mx = fmaxf(fmaxf(a1[0], a1[1]), fmaxf(b1[0], b1[1]));
        float av = (a1[0] + a1[1] + b1[0] + b1[1]) * 0.25f;
        float mw = fmaf(a1[0], mg[0], fmaf(a1[1], mg[1], fmaf(b1[0], mg[2], fmaf(b1[1], mg[3], mbv))));
        float aw = fmaf(a1[0], ag[0], fmaf(a1[1], ag[1], fmaf(b1[0], ag[2], fmaf(b1[1], ag[3], abv))));
        o[2] = mx * mw + av * aw;
    }
    {   // pixel 3: {a1[2],a1[3]; b1[2],b1[3]}
        float mx = fmaxf(fmaxf(a1[2], a1[3]), fmaxf(b1[2], b1[3]));
        float av = (a1[2] + a1[3] + b1[2] + b1[3]) * 0.25f;
        float mw = fmaf(a1[2], mg[0], fmaf(a1[3], mg[1], fmaf(b1[2], mg[2], fmaf(b1[3], mg[3], mbv))));
        float aw = fmaf(a1[2], ag[0], fmaf(a1[3], ag[1], fmaf(b1[2], ag[2], fmaf(b1[3], ag[3], abv))));
        o[3] = mx * mw + av * aw;
    }

    __builtin_nontemporal_store(o, reinterpret_cast<floatx4*>(out + (size_t)row * OW + 4 * t));
}

extern "C" void kernel_launch(void* const* d_in, const int* in_sizes, int n_in,
                              void* d_out, int out_size, void* d_ws, size_t ws_size,
                              hipStream_t stream) {
    const float* x  = (const float*)d_in[0];
    const float* mg = (const float*)d_in[1];
    const float* ag = (const float*)d_in[2];
    const float* mb = (const float*)d_in[3];
    const float* ab = (const float*)d_in[4];
    float* out = (float*)d_out;

    // total threads = B*C*OH * 32 = 16*128*128*32 = 8,388,608 -> 32768 blocks of 256
    const int total_threads = 16 * CC * OH * 32;
    dim3 grid(total_threads / 256);
    mixgb_kernel<<<grid, 256, 0, stream>>>(x, mg, ag, mb, ab, out);
}